// Round 3
// baseline (709.703 us; speedup 1.0000x reference)
//
#include <hip/hip_runtime.h>
#include <math.h>

typedef short v8s __attribute__((ext_vector_type(8)));
typedef float v4f __attribute__((ext_vector_type(4)));

#define NVOX 64000      // 40^3
#define NPAD 74088      // 42^3
#define P2   1764       // 42^2
#define GSTR 592704     // NPAD*8

__device__ __forceinline__ unsigned short bf16rne(float f){
  unsigned int u = __float_as_uint(f);
  u += 0x7FFFu + ((u >> 16) & 1u);
  return (unsigned short)(u >> 16);
}

// ---------------- projection: xp = proj_w @ x ; fp32 [c][n] and bf16 padded [g][p][8c]
// 2 blocks per 256 voxels: half = blockIdx&1 selects 32 output channels.
__global__ __launch_bounds__(256) void proj_k(const float* __restrict__ x,
                                              const float* __restrict__ pw,
                                              float* __restrict__ xp,
                                              short* __restrict__ xpt){
  int tid = threadIdx.x;
  int m = (blockIdx.x >> 1) * 256 + tid;
  int half = blockIdx.x & 1;
  float xv[64];
#pragma unroll
  for (int i = 0; i < 64; i++) xv[i] = x[(size_t)i * NVOX + m];
  int d = m / 1600; int r = m - d * 1600; int h = r / 40; int w = r - h * 40;
  int p = ((d + 1) * 42 + (h + 1)) * 42 + (w + 1);
  const float4* pw4 = (const float4*)pw;
  for (int g8 = half * 4; g8 < half * 4 + 4; g8++){
    v8s pk;
#pragma unroll
    for (int j = 0; j < 8; j++){
      int co = g8 * 8 + j;
      float acc = 0.f;
#pragma unroll
      for (int q = 0; q < 16; q++){
        float4 pv = pw4[co * 16 + q];   // wave-uniform -> scalar loads via K$
        acc = fmaf(pv.x, xv[4*q+0], acc);
        acc = fmaf(pv.y, xv[4*q+1], acc);
        acc = fmaf(pv.z, xv[4*q+2], acc);
        acc = fmaf(pv.w, xv[4*q+3], acc);
      }
      xp[(size_t)co * NVOX + m] = acc;
      pk[j] = (short)bf16rne(acc);
    }
    *(v8s*)(xpt + (size_t)g8 * GSTR + (size_t)p * 8) = pk;
  }
}

// ---------------- fused w+h box passes per (c,d) slice (zero pad)
__global__ __launch_bounds__(256) void boxwh_k(const float* __restrict__ in,
                                               float* __restrict__ out){
  __shared__ float s0[1600], s1[1600];
  size_t base = (size_t)blockIdx.x * 1600;
  int t = threadIdx.x;
  for (int e = t; e < 1600; e += 256) s0[e] = in[base + e];
  __syncthreads();
  for (int e = t; e < 1600; e += 256){
    int w = e % 40;
    float s = s0[e];
    if (w > 0)  s += s0[e - 1];
    if (w < 39) s += s0[e + 1];
    s1[e] = s;
  }
  __syncthreads();
  for (int e = t; e < 1600; e += 256){
    int h = e / 40;
    float s = s1[e];
    if (h > 0)  s += s1[e - 40];
    if (h < 39) s += s1[e + 40];
    out[base + e] = s;
  }
}
__global__ void boxd_k(const float* __restrict__ in, float* __restrict__ out){
  int g = blockIdx.x * 256 + threadIdx.x;
  int d = (g / 1600) % 40;
  float s = in[g];
  if (d > 0)  s += in[g - 1600];
  if (d < 39) s += in[g + 1600];
  out[g] = s * (1.f / 27.f);
}

// ---------------- kmeans init
__global__ void kinit_k(const float* __restrict__ xm, float* __restrict__ km,
                        int* __restrict__ cnt){
  int t = threadIdx.x;
  km[t] = xm[(size_t)(t & 63) * NVOX + (t >> 6)];
  if (t < 4) km[256 + t] = 1.f;
  if (t < 4) cnt[t] = 0;
  for (int j = 260 + t; j < 12 * 260; j += 256) km[j] = 0.f;
}

// ---------------- kmeans assign + reduce (mode 0) or idx+counts (mode 1)
// LDS reduce uses lane-rotated channel order: zero same-address collisions,
// only free 2-way bank aliasing. Total static LDS ~2.1 KB.
__global__ __launch_bounds__(256) void assign_k(const float* __restrict__ xm,
                                                const float* __restrict__ kin,
                                                float* __restrict__ kout,
                                                int* __restrict__ idx,
                                                int* __restrict__ cnt, int mode){
  __shared__ float s_cent[256];
  __shared__ float s_cc[4];
  __shared__ float s_red[260];
  int t = threadIdx.x, lane = t & 63;
  s_cent[t] = kin[t] / fmaxf(kin[256 + (t >> 6)], 1.f);
  for (int j = t; j < 260; j += 256) s_red[j] = 0.f;
  __syncthreads();
  if (t < 4){
    const float4* cc4 = (const float4*)(s_cent + t * 64);
    float s = 0.f;
#pragma unroll
    for (int q = 0; q < 16; q++){
      float4 v = cc4[q];
      s = fmaf(v.x, v.x, s); s = fmaf(v.y, v.y, s);
      s = fmaf(v.z, v.z, s); s = fmaf(v.w, v.w, s);
    }
    s_cc[t] = s;
  }
  __syncthreads();
  int n = blockIdx.x * 256 + t;
  float xv[64];
#pragma unroll
  for (int c = 0; c < 64; c++) xv[c] = xm[(size_t)c * NVOX + n];
  float d0 = 0.f, d1 = 0.f, d2 = 0.f, d3 = 0.f;
  const float4* c4 = (const float4*)s_cent;
#pragma unroll
  for (int q = 0; q < 16; q++){
    float4 p0 = c4[q], p1 = c4[16 + q], p2 = c4[32 + q], p3 = c4[48 + q];
    d0 = fmaf(p0.x, xv[4*q+0], d0); d0 = fmaf(p0.y, xv[4*q+1], d0);
    d0 = fmaf(p0.z, xv[4*q+2], d0); d0 = fmaf(p0.w, xv[4*q+3], d0);
    d1 = fmaf(p1.x, xv[4*q+0], d1); d1 = fmaf(p1.y, xv[4*q+1], d1);
    d1 = fmaf(p1.z, xv[4*q+2], d1); d1 = fmaf(p1.w, xv[4*q+3], d1);
    d2 = fmaf(p2.x, xv[4*q+0], d2); d2 = fmaf(p2.y, xv[4*q+1], d2);
    d2 = fmaf(p2.z, xv[4*q+2], d2); d2 = fmaf(p2.w, xv[4*q+3], d2);
    d3 = fmaf(p3.x, xv[4*q+0], d3); d3 = fmaf(p3.y, xv[4*q+1], d3);
    d3 = fmaf(p3.z, xv[4*q+2], d3); d3 = fmaf(p3.w, xv[4*q+3], d3);
  }
  float sc0 = s_cc[0] - 2.f * d0;
  float sc1 = s_cc[1] - 2.f * d1;
  float sc2 = s_cc[2] - 2.f * d2;
  float sc3 = s_cc[3] - 2.f * d3;
  int kb = 0; float bs = sc0;
  if (sc1 < bs){ bs = sc1; kb = 1; }
  if (sc2 < bs){ bs = sc2; kb = 2; }
  if (sc3 < bs){ bs = sc3; kb = 3; }
  if (mode){
    idx[n] = kb;
#pragma unroll
    for (int kk = 0; kk < 4; kk++){
      unsigned long long m = __ballot(kb == kk);
      if (lane == 0) atomicAdd(&cnt[kk], (int)__popcll(m));
    }
  } else {
    int kb64 = kb * 64;
#pragma unroll
    for (int c = 0; c < 64; c++){
      int cc = (c + lane) & 63;           // rotation: all lanes hit distinct slots
      atomicAdd(&s_red[kb64 + cc], xv[cc]);
    }
#pragma unroll
    for (int kk = 0; kk < 4; kk++){
      unsigned long long m = __ballot(kb == kk);
      if (lane == 0) atomicAdd(&s_red[256 + kk], (float)__popcll(m));
    }
    __syncthreads();
    for (int j = t; j < 260; j += 256) atomicAdd(&kout[j], s_red[j]);
  }
}

// ---------------- gating MLPs (1 block) + segment scan tail
__global__ void mlp_k(const float* __restrict__ km10,
                      const float* __restrict__ w1, const float* __restrict__ b1,
                      const float* __restrict__ w2, const float* __restrict__ b2,
                      const float* __restrict__ w3, const float* __restrict__ b3,
                      const float* __restrict__ u1, const float* __restrict__ c1,
                      const float* __restrict__ u2, const float* __restrict__ c2,
                      const float* __restrict__ u3, const float* __restrict__ c3,
                      float* __restrict__ wi, float* __restrict__ bias,
                      const int* __restrict__ cnt, int* __restrict__ segs,
                      int* __restrict__ curs){
  __shared__ float s_feat[256], s_h1[128], s_h2[128], s_g1[64], s_g2[64];
  int t = threadIdx.x;
  s_feat[t] = km10[t] / fmaxf(km10[256 + (t >> 6)], 1.f);
  __syncthreads();
  if (t < 128){
    float z = b1[t];
    for (int i = 0; i < 256; i++) z = fmaf(s_feat[i], w1[i * 128 + t], z);
    s_h1[t] = fmaxf(z, 0.f);
  }
  __syncthreads();
  if (t < 128){
    float z = b2[t];
    for (int i = 0; i < 128; i++) z = fmaf(s_h1[i], w2[i * 128 + t], z);
    s_h2[t] = fmaxf(z, 0.f);
  }
  __syncthreads();
  if (t < 108){
    float z = b3[t];
    for (int i = 0; i < 128; i++) z = fmaf(s_h2[i], w3[i * 108 + t], z);
    wi[t] = 1.f / (1.f + expf(-z));
  }
  if (t < 64){
    float z = c1[t];
    for (int i = 0; i < 256; i++) z = fmaf(s_feat[i], u1[i * 64 + t], z);
    s_g1[t] = fmaxf(z, 0.f);
  }
  __syncthreads();
  if (t < 64){
    float z = c2[t];
    for (int i = 0; i < 64; i++) z = fmaf(s_g1[i], u2[i * 64 + t], z);
    s_g2[t] = fmaxf(z, 0.f);
  }
  __syncthreads();
  {
    float z = c3[t];
    for (int i = 0; i < 64; i++) z = fmaf(s_g2[i], u3[i * 256 + t], z);
    bias[t] = z;
  }
  __syncthreads();
  if (t == 0){
    int s = 0;
    for (int k = 0; k < 4; k++){
      segs[k] = s; curs[k] = s;
      s += (cnt[k] + 63) & ~63;
    }
    segs[4] = s;
  }
}

// ---------------- base_w * wi -> bf16 [k][t][o][c]
__global__ void bwprep4_k(const float* __restrict__ bw, const float* __restrict__ wi,
                          short* __restrict__ bwb4){
  int e = blockIdx.x * 256 + threadIdx.x;        // 0 .. 442367
  int k = e / 110592; int r = e - k * 110592;
  int t = r >> 12; int rem = r & 4095;
  int o = rem >> 6; int c = rem & 63;
  bwb4[e] = (short)bf16rne(bw[(o * 64 + c) * 27 + t] * wi[k * 27 + t]);
}

// ---------------- sort voxels by cluster (wave-aggregated atomics)
__global__ __launch_bounds__(256) void scatter_k(const int* __restrict__ idx,
                                                 int* __restrict__ curs,
                                                 int* __restrict__ perm){
  int n = blockIdx.x * 256 + threadIdx.x;
  int lane = threadIdx.x & 63;
  int kb = idx[n];
#pragma unroll
  for (int kk = 0; kk < 4; kk++){
    unsigned long long m = __ballot(kb == kk);
    if (m){
      int leader = __ffsll((unsigned long long)m) - 1;
      int base = 0;
      if (lane == leader) base = atomicAdd(&curs[kk], (int)__popcll(m));
      base = __shfl(base, leader, 64);
      if (kb == kk){
        int rank = (int)__popcll(m & ((1ull << lane) - 1ull));
        perm[base + rank] = n;
      }
    }
  }
}

// ---------------- main dynamic conv: cluster-sorted, pure chained MFMA
__global__ __launch_bounds__(256) void conv_k(const short* __restrict__ xpt,
                                              const short* __restrict__ bwb4,
                                              const float* __restrict__ bias,
                                              const int* __restrict__ segs,
                                              const int* __restrict__ cnt,
                                              const int* __restrict__ perm,
                                              const float* __restrict__ x,
                                              const float* __restrict__ pa,
                                              float* __restrict__ out){
  static const int POFF[27] = {
    -P2-42-1, -P2-42, -P2-42+1, -P2-1, -P2, -P2+1, -P2+42-1, -P2+42, -P2+42+1,
    -42-1, -42, -42+1, -1, 0, 1, 42-1, 42, 42+1,
    P2-42-1, P2-42, P2-42+1, P2-1, P2, P2+1, P2+42-1, P2+42, P2+42+1 };
  __shared__ float s_bias[256];
  __shared__ int s_seg[5];
  __shared__ int s_cnt[4];
  int tid = threadIdx.x;
  if (tid < 256) s_bias[tid] = bias[tid];
  if (tid < 5) s_seg[tid] = segs[tid];
  if (tid < 4) s_cnt[tid] = cnt[tid];
  __syncthreads();
  int wv = tid >> 6, lane = tid & 63;
  int mh = wv & 1;                       // which half of output channels
  int slotbase = blockIdx.x * 128 + (wv >> 1) * 64;
  int k = 0;
  if (slotbase >= s_seg[1]) k = 1;
  if (slotbase >= s_seg[2]) k = 2;
  if (slotbase >= s_seg[3]) k = 3;
  int segk = s_seg[k], ck = s_cnt[k];
  int col = lane & 15, kg = lane >> 4;
  int n4[4], p4[4];
  bool valid[4];
#pragma unroll
  for (int nt = 0; nt < 4; nt++){
    int s = slotbase + nt * 16 + col;
    bool pad = (s >= segk + ck) || (ck == 0);
    if (s >= segk + ck) s = segk;
    int n = (ck > 0) ? perm[s] : 0;
    valid[nt] = !pad;
    n4[nt] = n;
    int d = n / 1600; int r = n - d * 1600; int h = r / 40; int w = r - h * 40;
    p4[nt] = ((d + 1) * 42 + (h + 1)) * 42 + (w + 1);
  }
  int ao0 = ((mh * 2 + 0) * 16 + col) * 64 + kg * 8;
  int ao1 = ((mh * 2 + 1) * 16 + col) * 64 + kg * 8;
  v4f acc[2][4];
#pragma unroll
  for (int m2 = 0; m2 < 2; m2++)
#pragma unroll
    for (int nt = 0; nt < 4; nt++) acc[m2][nt] = (v4f){0.f, 0.f, 0.f, 0.f};
#pragma unroll
  for (int kc = 0; kc < 2; kc++){
    const short* aW = bwb4 + (size_t)k * 110592 + kc * 32;
    const short* bg = xpt + (size_t)(kc * 4 + kg) * GSTR;
    const short* bp0 = bg + (size_t)p4[0] * 8;
    const short* bp1 = bg + (size_t)p4[1] * 8;
    const short* bp2 = bg + (size_t)p4[2] * 8;
    const short* bp3 = bg + (size_t)p4[3] * 8;
#pragma unroll
    for (int t = 0; t < 27; t++){
      int po8 = POFF[t] * 8;
      v8s a0 = *(const v8s*)(aW + t * 4096 + ao0);
      v8s a1 = *(const v8s*)(aW + t * 4096 + ao1);
      v8s b0 = *(const v8s*)(bp0 + po8);
      v8s b1 = *(const v8s*)(bp1 + po8);
      v8s b2 = *(const v8s*)(bp2 + po8);
      v8s b3 = *(const v8s*)(bp3 + po8);
      acc[0][0] = __builtin_amdgcn_mfma_f32_16x16x32_bf16(a0, b0, acc[0][0], 0, 0, 0);
      acc[1][0] = __builtin_amdgcn_mfma_f32_16x16x32_bf16(a1, b0, acc[1][0], 0, 0, 0);
      acc[0][1] = __builtin_amdgcn_mfma_f32_16x16x32_bf16(a0, b1, acc[0][1], 0, 0, 0);
      acc[1][1] = __builtin_amdgcn_mfma_f32_16x16x32_bf16(a1, b1, acc[1][1], 0, 0, 0);
      acc[0][2] = __builtin_amdgcn_mfma_f32_16x16x32_bf16(a0, b2, acc[0][2], 0, 0, 0);
      acc[1][2] = __builtin_amdgcn_mfma_f32_16x16x32_bf16(a1, b2, acc[1][2], 0, 0, 0);
      acc[0][3] = __builtin_amdgcn_mfma_f32_16x16x32_bf16(a0, b3, acc[0][3], 0, 0, 0);
      acc[1][3] = __builtin_amdgcn_mfma_f32_16x16x32_bf16(a1, b3, acc[1][3], 0, 0, 0);
    }
  }
  float pav = pa[0];
#pragma unroll
  for (int m2 = 0; m2 < 2; m2++){
    int mt = mh * 2 + m2;
#pragma unroll
    for (int nt = 0; nt < 4; nt++){
      if (!valid[nt]) continue;
      int n = n4[nt];
#pragma unroll
      for (int r = 0; r < 4; r++){
        int o = mt * 16 + kg * 4 + r;
        float val = acc[m2][nt][r] + s_bias[k * 64 + o];
        val = (val >= 0.f) ? val : pav * val;
        size_t off = (size_t)o * NVOX + n;
        out[off] = val + x[off];
      }
    }
  }
}

extern "C" void kernel_launch(void* const* d_in, const int* in_sizes, int n_in,
                              void* d_out, int out_size, void* d_ws, size_t ws_size,
                              hipStream_t stream){
  const float* x    = (const float*)d_in[0];
  const float* pw   = (const float*)d_in[1];
  const float* bw   = (const float*)d_in[2];
  const float* gkw1 = (const float*)d_in[3];
  const float* gkb1 = (const float*)d_in[4];
  const float* gkw2 = (const float*)d_in[5];
  const float* gkb2 = (const float*)d_in[6];
  const float* gkw3 = (const float*)d_in[7];
  const float* gkb3 = (const float*)d_in[8];
  const float* gbw1 = (const float*)d_in[9];
  const float* gbb1 = (const float*)d_in[10];
  const float* gbw2 = (const float*)d_in[11];
  const float* gbb2 = (const float*)d_in[12];
  const float* gbw3 = (const float*)d_in[13];
  const float* gbb3 = (const float*)d_in[14];
  const float* pa   = (const float*)d_in[15];
  float* outp = (float*)d_out;

  float* ws   = (float*)d_ws;
  float* XP   = ws;                                  // 4,096,000 f
  float* BU2  = ws + 4096000;                        // 4,096,000 f
  float* BU1  = ws + 8192000;                        // 4,096,000 f (xm)
  short* XPT  = (short*)(ws + 12288000);             // 4,741,632 s
  short* BWB4 = XPT + (size_t)NPAD * 64;             // 442,368 s
  float* KM   = (float*)(BWB4 + 442368);             // 3120 f
  float* WI   = KM + 3120;                           // 108 f
  float* BIAS = WI + 108;                            // 256 f
  int*   IDX  = (int*)(BIAS + 256);                  // 64,000 i
  int*   PERM = IDX + 64000;                         // 64,256 i
  int*   CNT  = PERM + 64256;                        // 4 i
  int*   SEGS = CNT + 4;                             // 5 i
  int*   CURS = SEGS + 5;                            // 4 i

  hipMemsetAsync(XPT, 0, (size_t)NPAD * 64 * 2, stream);
  proj_k<<<500, 256, 0, stream>>>(x, pw, XP, XPT);
  boxwh_k<<<2560, 256, 0, stream>>>(XP, BU2);
  boxd_k<<<16000, 256, 0, stream>>>(BU2, BU1);
  kinit_k<<<1, 256, 0, stream>>>(BU1, KM, CNT);
  for (int i = 0; i <= 10; i++)
    assign_k<<<250, 256, 0, stream>>>(BU1, KM + i * 260, KM + (i + 1) * 260, IDX, CNT,
                                      (i == 10) ? 1 : 0);
  mlp_k<<<1, 256, 0, stream>>>(KM + 10 * 260,
                               gkw1, gkb1, gkw2, gkb2, gkw3, gkb3,
                               gbw1, gbb1, gbw2, gbb2, gbw3, gbb3,
                               WI, BIAS, CNT, SEGS, CURS);
  bwprep4_k<<<1728, 256, 0, stream>>>(bw, WI, BWB4);
  scatter_k<<<250, 256, 0, stream>>>(IDX, CURS, PERM);
  conv_k<<<502, 256, 0, stream>>>(XPT, BWB4, BIAS, SEGS, CNT, PERM, x, pa, outp);
}

// Round 5
// 450.544 us; speedup vs baseline: 1.5752x; 1.5752x over previous
//
#include <hip/hip_runtime.h>
#include <math.h>

typedef short v8s __attribute__((ext_vector_type(8)));
typedef float v4f __attribute__((ext_vector_type(4)));

#define NVOX 64000      // 40^3
#define NPAD 74088      // 42^3
#define P2   1764       // 42^2
#define GSTR 592704     // NPAD*8

__device__ __forceinline__ unsigned short bf16rne(float f){
  unsigned int u = __float_as_uint(f);
  u += 0x7FFFu + ((u >> 16) & 1u);
  return (unsigned short)(u >> 16);
}

// ---------------- projection: xp = proj_w @ x ; fp32 [c][n] and bf16 padded [g][p][8c]
__global__ __launch_bounds__(256) void proj_k(const float* __restrict__ x,
                                              const float* __restrict__ pw,
                                              float* __restrict__ xp,
                                              short* __restrict__ xpt){
  int tid = threadIdx.x;
  int m = (blockIdx.x >> 1) * 256 + tid;
  int half = blockIdx.x & 1;
  float xv[64];
#pragma unroll
  for (int i = 0; i < 64; i++) xv[i] = x[(size_t)i * NVOX + m];
  int d = m / 1600; int r = m - d * 1600; int h = r / 40; int w = r - h * 40;
  int p = ((d + 1) * 42 + (h + 1)) * 42 + (w + 1);
  const float4* pw4 = (const float4*)pw;
  for (int g8 = half * 4; g8 < half * 4 + 4; g8++){
    v8s pk;
#pragma unroll
    for (int j = 0; j < 8; j++){
      int co = g8 * 8 + j;
      float acc = 0.f;
#pragma unroll
      for (int q = 0; q < 16; q++){
        float4 pv = pw4[co * 16 + q];   // wave-uniform -> scalar K$ loads
        acc = fmaf(pv.x, xv[4*q+0], acc);
        acc = fmaf(pv.y, xv[4*q+1], acc);
        acc = fmaf(pv.z, xv[4*q+2], acc);
        acc = fmaf(pv.w, xv[4*q+3], acc);
      }
      xp[(size_t)co * NVOX + m] = acc;
      pk[j] = (short)bf16rne(acc);
    }
    *(v8s*)(xpt + (size_t)g8 * GSTR + (size_t)p * 8) = pk;
  }
}

// ---------------- fused w+h box passes per (c,d) slice (zero pad)
__global__ __launch_bounds__(256) void boxwh_k(const float* __restrict__ in,
                                               float* __restrict__ out){
  __shared__ float s0[1600], s1[1600];
  size_t base = (size_t)blockIdx.x * 1600;
  int t = threadIdx.x;
  for (int e = t; e < 1600; e += 256) s0[e] = in[base + e];
  __syncthreads();
  for (int e = t; e < 1600; e += 256){
    int w = e % 40;
    float s = s0[e];
    if (w > 0)  s += s0[e - 1];
    if (w < 39) s += s0[e + 1];
    s1[e] = s;
  }
  __syncthreads();
  for (int e = t; e < 1600; e += 256){
    int h = e / 40;
    float s = s1[e];
    if (h > 0)  s += s1[e - 40];
    if (h < 39) s += s1[e + 40];
    out[base + e] = s;
  }
}
__global__ void boxd_k(const float* __restrict__ in, float* __restrict__ out){
  int g = blockIdx.x * 256 + threadIdx.x;
  int d = (g / 1600) % 40;
  float s = in[g];
  if (d > 0)  s += in[g - 1600];
  if (d < 39) s += in[g + 1600];
  out[g] = s * (1.f / 27.f);
}

// ---------------- kmeans init
__global__ void kinit_k(const float* __restrict__ xm, float* __restrict__ km){
  int t = threadIdx.x;
  km[t] = xm[(size_t)(t & 63) * NVOX + (t >> 6)];
  if (t < 4) km[256 + t] = 1.f;
  for (int j = 260 + t; j < 12 * 260; j += 256) km[j] = 0.f;
}

// ---------------- kmeans assign + reduce (mode 0) or idx write (mode 1)
// Reduction: xv -> LDS (static idx), lane=channel sums its wave's 64 voxels
// with predicated adds. No dynamic register indexing, no same-address atomics.
__global__ __launch_bounds__(128) void assign_k(const float* __restrict__ xm,
                                                const float* __restrict__ kin,
                                                float* __restrict__ kout,
                                                int* __restrict__ idx, int mode){
  __shared__ float s_cent[256];
  __shared__ float s_cc[4];
  __shared__ float s_red[260];
  __shared__ float s_x[128 * 65];
  __shared__ int   s_kb[128];
  int t = threadIdx.x, lane = t & 63, wv = t >> 6;
  for (int j = t; j < 256; j += 128) s_cent[j] = kin[j] / fmaxf(kin[256 + (j >> 6)], 1.f);
  for (int j = t; j < 260; j += 128) s_red[j] = 0.f;
  __syncthreads();
  if (t < 4){
    const float4* cc4 = (const float4*)(s_cent + t * 64);
    float s = 0.f;
#pragma unroll
    for (int q = 0; q < 16; q++){
      float4 v = cc4[q];
      s = fmaf(v.x, v.x, s); s = fmaf(v.y, v.y, s);
      s = fmaf(v.z, v.z, s); s = fmaf(v.w, v.w, s);
    }
    s_cc[t] = s;
  }
  __syncthreads();
  int n = blockIdx.x * 128 + t;
  float xv[64];
#pragma unroll
  for (int c = 0; c < 64; c++) xv[c] = xm[(size_t)c * NVOX + n];
  float d0 = 0.f, d1 = 0.f, d2 = 0.f, d3 = 0.f;
  const float4* c4 = (const float4*)s_cent;
#pragma unroll
  for (int q = 0; q < 16; q++){
    float4 p0 = c4[q], p1 = c4[16 + q], p2 = c4[32 + q], p3 = c4[48 + q];
    d0 = fmaf(p0.x, xv[4*q+0], d0); d0 = fmaf(p0.y, xv[4*q+1], d0);
    d0 = fmaf(p0.z, xv[4*q+2], d0); d0 = fmaf(p0.w, xv[4*q+3], d0);
    d1 = fmaf(p1.x, xv[4*q+0], d1); d1 = fmaf(p1.y, xv[4*q+1], d1);
    d1 = fmaf(p1.z, xv[4*q+2], d1); d1 = fmaf(p1.w, xv[4*q+3], d1);
    d2 = fmaf(p2.x, xv[4*q+0], d2); d2 = fmaf(p2.y, xv[4*q+1], d2);
    d2 = fmaf(p2.z, xv[4*q+2], d2); d2 = fmaf(p2.w, xv[4*q+3], d2);
    d3 = fmaf(p3.x, xv[4*q+0], d3); d3 = fmaf(p3.y, xv[4*q+1], d3);
    d3 = fmaf(p3.z, xv[4*q+2], d3); d3 = fmaf(p3.w, xv[4*q+3], d3);
  }
  float sc0 = s_cc[0] - 2.f * d0;
  float sc1 = s_cc[1] - 2.f * d1;
  float sc2 = s_cc[2] - 2.f * d2;
  float sc3 = s_cc[3] - 2.f * d3;
  int kb = 0; float bs = sc0;
  if (sc1 < bs){ bs = sc1; kb = 1; }
  if (sc2 < bs){ bs = sc2; kb = 2; }
  if (sc3 < bs){ bs = sc3; kb = 3; }
  if (mode){
    idx[n] = kb;
  } else {
    s_kb[t] = kb;
#pragma unroll
    for (int c = 0; c < 64; c++) s_x[t * 65 + c] = xv[c];   // banks (t+c)&31: free 2-way
    __syncthreads();
    float a0 = 0.f, a1 = 0.f, a2 = 0.f, a3 = 0.f;
    int rowbase = wv * 64;
#pragma unroll 16
    for (int j = 0; j < 64; j++){
      float v = s_x[(rowbase + j) * 65 + lane];             // conflict-free columns
      int kj = s_kb[rowbase + j];                           // broadcast
      a0 += (kj == 0) ? v : 0.f;
      a1 += (kj == 1) ? v : 0.f;
      a2 += (kj == 2) ? v : 0.f;
      a3 += (kj == 3) ? v : 0.f;
    }
    atomicAdd(&s_red[lane], a0);
    atomicAdd(&s_red[64 + lane], a1);
    atomicAdd(&s_red[128 + lane], a2);
    atomicAdd(&s_red[192 + lane], a3);
#pragma unroll
    for (int kk = 0; kk < 4; kk++){
      unsigned long long m = __ballot(kb == kk);
      if (lane == 0) atomicAdd(&s_red[256 + kk], (float)__popcll(m));
    }
    __syncthreads();
    for (int j = t; j < 260; j += 128) atomicAdd(&kout[j], s_red[j]);
  }
}

// ---------------- gating MLPs (1 block, 256 thr)
__global__ void mlp_k(const float* __restrict__ km10,
                      const float* __restrict__ w1, const float* __restrict__ b1,
                      const float* __restrict__ w2, const float* __restrict__ b2,
                      const float* __restrict__ w3, const float* __restrict__ b3,
                      const float* __restrict__ u1, const float* __restrict__ c1,
                      const float* __restrict__ u2, const float* __restrict__ c2,
                      const float* __restrict__ u3, const float* __restrict__ c3,
                      float* __restrict__ wi, float* __restrict__ bias){
  __shared__ float s_feat[256], s_h1[128], s_h2[128], s_g1[64], s_g2[64];
  int t = threadIdx.x;
  s_feat[t] = km10[t] / fmaxf(km10[256 + (t >> 6)], 1.f);
  __syncthreads();
  if (t < 128){
    float z = b1[t];
    for (int i = 0; i < 256; i++) z = fmaf(s_feat[i], w1[i * 128 + t], z);
    s_h1[t] = fmaxf(z, 0.f);
  }
  __syncthreads();
  if (t < 128){
    float z = b2[t];
    for (int i = 0; i < 128; i++) z = fmaf(s_h1[i], w2[i * 128 + t], z);
    s_h2[t] = fmaxf(z, 0.f);
  }
  __syncthreads();
  if (t < 108){
    float z = b3[t];
    for (int i = 0; i < 128; i++) z = fmaf(s_h2[i], w3[i * 108 + t], z);
    wi[t] = 1.f / (1.f + expf(-z));
  }
  if (t < 64){
    float z = c1[t];
    for (int i = 0; i < 256; i++) z = fmaf(s_feat[i], u1[i * 64 + t], z);
    s_g1[t] = fmaxf(z, 0.f);
  }
  __syncthreads();
  if (t < 64){
    float z = c2[t];
    for (int i = 0; i < 64; i++) z = fmaf(s_g1[i], u2[i * 64 + t], z);
    s_g2[t] = fmaxf(z, 0.f);
  }
  __syncthreads();
  {
    float z = c3[t];
    for (int i = 0; i < 64; i++) z = fmaf(s_g2[i], u3[i * 256 + t], z);
    bias[t] = z;
  }
}

// ---------------- base_w fp32 (o,c,t) -> bf16 [t][o][c]
__global__ void bwprep_k(const float* __restrict__ bw, short* __restrict__ bwb){
  int e = blockIdx.x * 256 + threadIdx.x;           // 0 .. 110591
  int t = e >> 12; int rem = e & 4095;
  int o = rem >> 6; int c = rem & 63;
  bwb[e] = (short)bf16rne(bw[(o * 64 + c) * 27 + t]);
}

// ---------------- main dynamic conv: in-order voxels, 4 waves = 2 mh x 2 kc
// per 64-voxel column tile; K-split halves the per-wave chain, LDS reduce.
__global__ __launch_bounds__(256) void conv_k(const short* __restrict__ xpt,
                                              const short* __restrict__ bwb,
                                              const float* __restrict__ wi,
                                              const float* __restrict__ bias,
                                              const int* __restrict__ idx,
                                              const float* __restrict__ x,
                                              const float* __restrict__ pa,
                                              float* __restrict__ out){
  static const int POFF[27] = {
    -P2-42-1, -P2-42, -P2-42+1, -P2-1, -P2, -P2+1, -P2+42-1, -P2+42, -P2+42+1,
    -42-1, -42, -42+1, -1, 0, 1, 42-1, 42, 42+1,
    P2-42-1, P2-42, P2-42+1, P2-1, P2, P2+1, P2+42-1, P2+42, P2+42+1 };
  __shared__ float s_wi[108];
  __shared__ float s_bias[256];
  __shared__ float s_acc[64 * 68];
  int tid = threadIdx.x;
  for (int j = tid; j < 108; j += 256) s_wi[j] = wi[j];
  s_bias[tid] = bias[tid];
  __syncthreads();
  int wv = tid >> 6, lane = tid & 63;
  int kc = wv & 1, mh = wv >> 1;
  int col = lane & 15, kg = lane >> 4;
  int vb = blockIdx.x * 64;
  int p4[4], ki4[4];
#pragma unroll
  for (int nt = 0; nt < 4; nt++){
    int v = vb + nt * 16 + col;
    ki4[nt] = idx[v];
    int d = v / 1600; int r = v - d * 1600; int h = r / 40; int w = r - h * 40;
    p4[nt] = ((d + 1) * 42 + (h + 1)) * 42 + (w + 1);
  }
  const short* bg = xpt + (size_t)(kc * 4 + kg) * GSTR;
  const short* bp0 = bg + (size_t)p4[0] * 8;
  const short* bp1 = bg + (size_t)p4[1] * 8;
  const short* bp2 = bg + (size_t)p4[2] * 8;
  const short* bp3 = bg + (size_t)p4[3] * 8;
  int ao0 = (mh * 32 + col) * 64 + kc * 32 + kg * 8;
  int ao1 = ao0 + 16 * 64;
  v4f acc[2][4];
#pragma unroll
  for (int m2 = 0; m2 < 2; m2++)
#pragma unroll
    for (int nt = 0; nt < 4; nt++) acc[m2][nt] = (v4f){0.f, 0.f, 0.f, 0.f};
  v4f zero = {0.f, 0.f, 0.f, 0.f};
#pragma unroll 9
  for (int t = 0; t < 27; t++){
    int po8 = POFF[t] * 8;
    v8s a0 = *(const v8s*)(bwb + t * 4096 + ao0);
    v8s a1 = *(const v8s*)(bwb + t * 4096 + ao1);
    v8s b0 = *(const v8s*)(bp0 + po8);
    v8s b1 = *(const v8s*)(bp1 + po8);
    v8s b2 = *(const v8s*)(bp2 + po8);
    v8s b3 = *(const v8s*)(bp3 + po8);
    float wk0 = s_wi[ki4[0] * 27 + t];
    float wk1 = s_wi[ki4[1] * 27 + t];
    float wk2 = s_wi[ki4[2] * 27 + t];
    float wk3 = s_wi[ki4[3] * 27 + t];
    v4f tp;
    tp = __builtin_amdgcn_mfma_f32_16x16x32_bf16(a0, b0, zero, 0, 0, 0); acc[0][0] += tp * wk0;
    tp = __builtin_amdgcn_mfma_f32_16x16x32_bf16(a1, b0, zero, 0, 0, 0); acc[1][0] += tp * wk0;
    tp = __builtin_amdgcn_mfma_f32_16x16x32_bf16(a0, b1, zero, 0, 0, 0); acc[0][1] += tp * wk1;
    tp = __builtin_amdgcn_mfma_f32_16x16x32_bf16(a1, b1, zero, 0, 0, 0); acc[1][1] += tp * wk1;
    tp = __builtin_amdgcn_mfma_f32_16x16x32_bf16(a0, b2, zero, 0, 0, 0); acc[0][2] += tp * wk2;
    tp = __builtin_amdgcn_mfma_f32_16x16x32_bf16(a1, b2, zero, 0, 0, 0); acc[1][2] += tp * wk2;
    tp = __builtin_amdgcn_mfma_f32_16x16x32_bf16(a0, b3, zero, 0, 0, 0); acc[0][3] += tp * wk3;
    tp = __builtin_amdgcn_mfma_f32_16x16x32_bf16(a1, b3, zero, 0, 0, 0); acc[1][3] += tp * wk3;
  }
  __syncthreads();
  if (kc == 1){
#pragma unroll
    for (int m2 = 0; m2 < 2; m2++)
#pragma unroll
      for (int nt = 0; nt < 4; nt++)
        *(v4f*)(&s_acc[(nt * 16 + col) * 68 + mh * 32 + m2 * 16 + kg * 4]) = acc[m2][nt];
  }
  __syncthreads();
  if (kc == 0){
    float pav = pa[0];
#pragma unroll
    for (int m2 = 0; m2 < 2; m2++){
#pragma unroll
      for (int nt = 0; nt < 4; nt++){
        v4f other = *(const v4f*)(&s_acc[(nt * 16 + col) * 68 + mh * 32 + m2 * 16 + kg * 4]);
        v4f sum = acc[m2][nt] + other;
        int n = vb + nt * 16 + col;
#pragma unroll
        for (int r = 0; r < 4; r++){
          int o = mh * 32 + m2 * 16 + kg * 4 + r;
          float val = sum[r] + s_bias[ki4[nt] * 64 + o];
          val = (val >= 0.f) ? val : pav * val;
          size_t off = (size_t)o * NVOX + n;
          out[off] = val + x[off];
        }
      }
    }
  }
}

extern "C" void kernel_launch(void* const* d_in, const int* in_sizes, int n_in,
                              void* d_out, int out_size, void* d_ws, size_t ws_size,
                              hipStream_t stream){
  const float* x    = (const float*)d_in[0];
  const float* pw   = (const float*)d_in[1];
  const float* bw   = (const float*)d_in[2];
  const float* gkw1 = (const float*)d_in[3];
  const float* gkb1 = (const float*)d_in[4];
  const float* gkw2 = (const float*)d_in[5];
  const float* gkb2 = (const float*)d_in[6];
  const float* gkw3 = (const float*)d_in[7];
  const float* gkb3 = (const float*)d_in[8];
  const float* gbw1 = (const float*)d_in[9];
  const float* gbb1 = (const float*)d_in[10];
  const float* gbw2 = (const float*)d_in[11];
  const float* gbb2 = (const float*)d_in[12];
  const float* gbw3 = (const float*)d_in[13];
  const float* gbb3 = (const float*)d_in[14];
  const float* pa   = (const float*)d_in[15];
  float* outp = (float*)d_out;

  float* ws   = (float*)d_ws;
  float* XP   = ws;                                  // 4,096,000 f
  float* BU2  = ws + 4096000;                        // 4,096,000 f
  float* BU1  = ws + 8192000;                        // 4,096,000 f (xm)
  short* XPT  = (short*)(ws + 12288000);             // 4,741,632 s
  short* BWB  = XPT + (size_t)NPAD * 64;             // 110,592 s
  float* KM   = (float*)(BWB + 110592);              // 3120 f
  float* WI   = KM + 3120;                           // 108 f
  float* BIAS = WI + 108;                            // 256 f
  int*   IDX  = (int*)(BIAS + 256);                  // 64,000 i

  hipMemsetAsync(XPT, 0, (size_t)NPAD * 64 * 2, stream);
  proj_k<<<500, 256, 0, stream>>>(x, pw, XP, XPT);
  boxwh_k<<<2560, 256, 0, stream>>>(XP, BU2);
  boxd_k<<<16000, 256, 0, stream>>>(BU2, BU1);
  kinit_k<<<1, 256, 0, stream>>>(BU1, KM);
  for (int i = 0; i <= 10; i++)
    assign_k<<<500, 128, 0, stream>>>(BU1, KM + i * 260, KM + (i + 1) * 260, IDX,
                                      (i == 10) ? 1 : 0);
  mlp_k<<<1, 256, 0, stream>>>(KM + 10 * 260,
                               gkw1, gkb1, gkw2, gkb2, gkw3, gkb3,
                               gbw1, gbb1, gbw2, gbb2, gbw3, gbb3,
                               WI, BIAS);
  bwprep_k<<<432, 256, 0, stream>>>(bw, BWB);
  conv_k<<<1000, 256, 0, stream>>>(XPT, BWB, WI, BIAS, IDX, x, pa, outp);
}